// Round 6
// baseline (127.508 us; speedup 1.0000x reference)
//
#include <hip/hip_runtime.h>
#include <math.h>

#define S 4096
#define B 16
#define CK 256          // tile cols
#define NCHUNK (S / CK) // 16
#define R 8             // attention rows per wave

// ---------------------------------------------------------------------------
// Fused QKV skinny GEMM — async global->LDS (T3 2-phase pipeline).
// Grid: 768 blocks = 3 mats x 256 groups(16 rows x 16 batches).
// Per tile (256 cols): stage W[16x256] + x[16x256] into LDS via
// global_load_lds_dwordx4 (DMA queue holds bytes in flight — compiler-proof,
// unlike VGPR prefetch which R5 proved gets sunk by regalloc, VGPR=56).
// Double-buffered: tile c+1's 32 KB DMA overlaps tile c's compute; one
// vmcnt(0)+barrier per tile. 2 blocks/CU (LDS-capped) x 32 KB in flight
// saturates HBM by Little's law.
// ---------------------------------------------------------------------------
__global__ __launch_bounds__(256, 2) void qkv_kernel(
    const float* __restrict__ x,
    const float* __restrict__ Wq, const float* __restrict__ bq,
    const float* __restrict__ Wk, const float* __restrict__ bk,
    const float* __restrict__ Wv, const float* __restrict__ bv,
    float* __restrict__ q, float* __restrict__ k, float* __restrict__ v)
{
    __shared__ float wbuf[2][16 * CK];   // 16 KB per buffer
    __shared__ float xbuf[2][B * CK];    // 16 KB per buffer (64 KB total)

    const int tid  = threadIdx.x;
    const int lane = tid & 63;
    const int wave = tid >> 6;
    const int bx   = blockIdx.x;        // 0..767
    const int mat  = bx >> 8;           // 0:q 1:k 2:v
    const int og   = bx & 255;          // 16-row group
    const int o0   = og * 16;

    const float* W    = (mat == 0) ? Wq : (mat == 1) ? Wk : Wv;
    const float* bias = (mat == 0) ? bq : (mat == 1) ? bk : bv;
    float*       out  = (mat == 0) ? q  : (mat == 1) ? k  : v;

    float acc[4][16];
    #pragma unroll
    for (int r = 0; r < 4; ++r)
        #pragma unroll
        for (int b = 0; b < 16; ++b) acc[r][b] = 0.f;

    // Stage tile c into buffer bufi. Wave w, issue j covers row (j*4+w):
    // LDS dst is wave-uniform (HW adds lane*16B); global src is per-lane.
    #define QKV_STAGE(bufi, c)                                                \
    {                                                                         \
        _Pragma("unroll")                                                     \
        for (int j = 0; j < 4; ++j) {                                         \
            const int row = j * 4 + wave;                                     \
            const float* gw = &W[(size_t)(o0 + row) * S + (c) * CK + lane*4]; \
            __builtin_amdgcn_global_load_lds(                                 \
                (const __attribute__((address_space(1))) void*)gw,            \
                (__attribute__((address_space(3))) void*)&wbuf[bufi][row*CK], \
                16, 0, 0);                                                    \
            const float* gx = &x[(size_t)row * S + (c) * CK + lane * 4];      \
            __builtin_amdgcn_global_load_lds(                                 \
                (const __attribute__((address_space(1))) void*)gx,            \
                (__attribute__((address_space(3))) void*)&xbuf[bufi][row*CK], \
                16, 0, 0);                                                    \
        }                                                                     \
    }

    // Compute tile from buffer bufi: wave owns rows 4*wave..4*wave+3,
    // lane owns cols lane*4..lane*4+3 (contiguous b128 reads, conflict-free).
    #define QKV_COMPUTE(bufi)                                                 \
    {                                                                         \
        float4 wv0 = *(const float4*)&wbuf[bufi][(4*wave + 0)*CK + lane*4];   \
        float4 wv1 = *(const float4*)&wbuf[bufi][(4*wave + 1)*CK + lane*4];   \
        float4 wv2 = *(const float4*)&wbuf[bufi][(4*wave + 2)*CK + lane*4];   \
        float4 wv3 = *(const float4*)&wbuf[bufi][(4*wave + 3)*CK + lane*4];   \
        _Pragma("unroll")                                                     \
        for (int b = 0; b < 16; ++b) {                                        \
            float4 xv = *(const float4*)&xbuf[bufi][b * CK + lane * 4];       \
            acc[0][b] = fmaf(wv0.x, xv.x, acc[0][b]);                         \
            acc[0][b] = fmaf(wv0.y, xv.y, acc[0][b]);                         \
            acc[0][b] = fmaf(wv0.z, xv.z, acc[0][b]);                         \
            acc[0][b] = fmaf(wv0.w, xv.w, acc[0][b]);                         \
            acc[1][b] = fmaf(wv1.x, xv.x, acc[1][b]);                         \
            acc[1][b] = fmaf(wv1.y, xv.y, acc[1][b]);                         \
            acc[1][b] = fmaf(wv1.z, xv.z, acc[1][b]);                         \
            acc[1][b] = fmaf(wv1.w, xv.w, acc[1][b]);                         \
            acc[2][b] = fmaf(wv2.x, xv.x, acc[2][b]);                         \
            acc[2][b] = fmaf(wv2.y, xv.y, acc[2][b]);                         \
            acc[2][b] = fmaf(wv2.z, xv.z, acc[2][b]);                         \
            acc[2][b] = fmaf(wv2.w, xv.w, acc[2][b]);                         \
            acc[3][b] = fmaf(wv3.x, xv.x, acc[3][b]);                         \
            acc[3][b] = fmaf(wv3.y, xv.y, acc[3][b]);                         \
            acc[3][b] = fmaf(wv3.z, xv.z, acc[3][b]);                         \
            acc[3][b] = fmaf(wv3.w, xv.w, acc[3][b]);                         \
        }                                                                     \
    }

    // prologue: tile 0
    QKV_STAGE(0, 0);
    asm volatile("s_waitcnt vmcnt(0)" ::: "memory");
    __syncthreads();

    #pragma unroll 1
    for (int c = 0; c < NCHUNK - 1; ++c) {
        QKV_STAGE((c + 1) & 1, c + 1);   // issue next tile's DMA first
        QKV_COMPUTE(c & 1);              // compute current tile
        asm volatile("s_waitcnt vmcnt(0)" ::: "memory");
        __syncthreads();                 // next tile ready; cur fully read
    }
    QKV_COMPUTE((NCHUNK - 1) & 1);

    #undef QKV_STAGE
    #undef QKV_COMPUTE

    // cross-lane reduction; lane (r*16+b) writes output (b, o0+4*wave+r)
    #pragma unroll
    for (int r = 0; r < 4; ++r) {
        #pragma unroll
        for (int b = 0; b < 16; ++b) {
            float s = acc[r][b];
            #pragma unroll
            for (int off = 32; off; off >>= 1) s += __shfl_xor(s, off, 64);
            if (lane == r * 16 + b)
                out[(size_t)b * S + o0 + 4 * wave + r]
                    = s + bias[o0 + 4 * wave + r];
        }
    }
}

// ---------------------------------------------------------------------------
// Inclusive prefix max/min of k per batch row. 16 blocks x 256 threads.
// ---------------------------------------------------------------------------
__global__ __launch_bounds__(256) void scan_kernel(
    const float* __restrict__ k,
    float* __restrict__ rmax, float* __restrict__ rmin)
{
    __shared__ float smax[256], smin[256];
    const int b = blockIdx.x, t = threadIdx.x;
    const float* kb = k + b * S;

    float seg[16];
    float lmax = -INFINITY, lmin = INFINITY;
    #pragma unroll
    for (int e = 0; e < 16; ++e) {
        seg[e] = kb[t * 16 + e];
        lmax = fmaxf(lmax, seg[e]);
        lmin = fminf(lmin, seg[e]);
    }
    smax[t] = lmax; smin[t] = lmin;
    __syncthreads();
    for (int off = 1; off < 256; off <<= 1) {
        float vx = (t >= off) ? smax[t - off] : -INFINITY;
        float vn = (t >= off) ? smin[t - off] :  INFINITY;
        __syncthreads();
        smax[t] = fmaxf(smax[t], vx);
        smin[t] = fminf(smin[t], vn);
        __syncthreads();
    }
    float runmax = (t > 0) ? smax[t - 1] : -INFINITY;
    float runmin = (t > 0) ? smin[t - 1] :  INFINITY;
    #pragma unroll
    for (int e = 0; e < 16; ++e) {
        runmax = fmaxf(runmax, seg[e]);
        runmin = fminf(runmin, seg[e]);
        rmax[b * S + t * 16 + e] = runmax;
        rmin[b * S + t * 16 + e] = runmin;
    }
}

// ---------------------------------------------------------------------------
// d=1 causal attention, single pass (row max known from prefix scan).
// Wave handles R=8 consecutive rows of one batch, sharing k/v loads.
// ---------------------------------------------------------------------------
__global__ __launch_bounds__(256) void attn_kernel(
    const float* __restrict__ q, const float* __restrict__ k,
    const float* __restrict__ v,
    const float* __restrict__ rmax, const float* __restrict__ rmin,
    float* __restrict__ out)
{
    const int tid = threadIdx.x, lane = tid & 63, wave = tid >> 6;
    const int task = blockIdx.x * 4 + wave;     // 0..8191
    const int b    = task & 15;
    const int rbi  = task >> 4;                 // 0..511
    const int i0   = (511 - rbi) * R;           // descending: big rows first
    const float* kb = k + b * S;
    const float* vb = v + b * S;
    const float LOG2E = 1.4426950408889634f;

    float a[R], cc[R], den[R], num[R];
    #pragma unroll
    for (int r = 0; r < R; ++r) {
        float qi = q[b * S + i0 + r];
        float m  = (qi >= 0.f) ? qi * rmax[b * S + i0 + r]
                               : qi * rmin[b * S + i0 + r];
        a[r]  = qi * LOG2E;
        cc[r] = -m * LOG2E;
        den[r] = 0.f; num[r] = 0.f;
    }

    const int nfull = (i0 + 1) >> 8;            // full 256-wide chunks
    #pragma unroll 1
    for (int it = 0; it < nfull; ++it) {
        const int j = it * 256 + lane * 4;
        float4 k4 = *(const float4*)&kb[j];
        float4 v4 = *(const float4*)&vb[j];
        #pragma unroll
        for (int jj = 0; jj < 4; ++jj) {
            float kx = (&k4.x)[jj], vx = (&v4.x)[jj];
            #pragma unroll
            for (int r = 0; r < R; ++r) {
                float e = exp2f(fmaf(a[r], kx, cc[r]));
                den[r] += e;
                num[r] = fmaf(e, vx, num[r]);
            }
        }
    }
    // masked tail
    const int imax = i0 + R - 1;
    for (int j = nfull * 256 + lane; j <= imax; j += 64) {
        float kx = kb[j], vx = vb[j];
        #pragma unroll
        for (int r = 0; r < R; ++r) {
            float e = (j <= i0 + r) ? exp2f(fmaf(a[r], kx, cc[r])) : 0.f;
            den[r] += e;
            num[r] = fmaf(e, vx, num[r]);
        }
    }

    #pragma unroll
    for (int r = 0; r < R; ++r) {
        float d = den[r], n = num[r];
        #pragma unroll
        for (int off = 32; off; off >>= 1) {
            d += __shfl_xor(d, off, 64);
            n += __shfl_xor(n, off, 64);
        }
        if (lane == r) out[b * S + i0 + r] = n / d;
    }
}

extern "C" void kernel_launch(void* const* d_in, const int* in_sizes, int n_in,
                              void* d_out, int out_size, void* d_ws, size_t ws_size,
                              hipStream_t stream) {
    const float* x  = (const float*)d_in[0];
    const float* Wq = (const float*)d_in[1];
    const float* bq = (const float*)d_in[2];
    const float* Wk = (const float*)d_in[3];
    const float* bk = (const float*)d_in[4];
    const float* Wv = (const float*)d_in[5];
    const float* bv = (const float*)d_in[6];
    float* out = (float*)d_out;

    float* ws   = (float*)d_ws;
    float* q    = ws;                // 16*4096
    float* k    = ws + 65536;
    float* v    = ws + 131072;
    float* rmax = ws + 196608;
    float* rmin = ws + 262144;       // total 1.25 MB scratch

    qkv_kernel<<<768, 256, 0, stream>>>(x, Wq, bq, Wk, bk, Wv, bv, q, k, v);
    scan_kernel<<<16, 256, 0, stream>>>(k, rmax, rmin);
    attn_kernel<<<2048, 256, 0, stream>>>(q, k, v, rmax, rmin, out);
}